// Round 6
// baseline (365.752 us; speedup 1.0000x reference)
//
#include <hip/hip_runtime.h>
#include <hip/hip_bf16.h>
#include <stdint.h>

#define NUM_EMB 4096
#define EMB_DIM 256
#define NVEC 65536                     // 64*32*32
#define OUT0_SIZE (NVEC * EMB_DIM)     // z_q_ste elements; loss scalar follows
#define MTILE 128                      // z rows per block
#define NTILE 64                       // codebook entries per iteration
#define DCONST 0.0625f                 // positivity shift for packed distance

typedef __bf16 bf16x8 __attribute__((ext_vector_type(8)));
typedef float floatx16 __attribute__((ext_vector_type(16)));

static __device__ __forceinline__ unsigned int f2bf(float f) {
  unsigned int u = __float_as_uint(f);
  return (u + 0x7fffu + ((u >> 16) & 1u)) >> 16;  // RNE fp32->bf16
}

static __device__ __forceinline__ uint4 pack_bf8(float4 a, float4 b) {
  uint4 r;
  r.x = f2bf(a.x) | (f2bf(a.y) << 16);
  r.y = f2bf(a.z) | (f2bf(a.w) << 16);
  r.z = f2bf(b.x) | (f2bf(b.y) << 16);
  r.w = f2bf(b.z) | (f2bf(b.w) << 16);
  return r;
}

// Prep: codebook fp32 -> bf16 (ws), ||e||^2 + DCONST (ws), zero loss slot.
__global__ void __launch_bounds__(256) vq_prep(const float* __restrict__ cbf,
                                               unsigned short* __restrict__ cbb,
                                               float* __restrict__ enorm,
                                               float* __restrict__ out) {
  int w = threadIdx.x >> 6;
  int lane = threadIdx.x & 63;
  int row = blockIdx.x * 4 + w;
  float4 v = ((const float4*)(cbf + (size_t)row * EMB_DIM))[lane];
  float ss = v.x * v.x + v.y * v.y + v.z * v.z + v.w * v.w;
  ushort4 b;
  b.x = (unsigned short)f2bf(v.x);
  b.y = (unsigned short)f2bf(v.y);
  b.z = (unsigned short)f2bf(v.z);
  b.w = (unsigned short)f2bf(v.w);
  ((ushort4*)(cbb + (size_t)row * EMB_DIM))[lane] = b;
#pragma unroll
  for (int m = 1; m < 64; m <<= 1) ss += __shfl_xor(ss, m, 64);
  if (lane == 0) enorm[row] = ss + DCONST;
  if (blockIdx.x == 0 && threadIdx.x == 0) out[OUT0_SIZE] = 0.0f;
}

// Main: distance-GEMM streaming B directly from L2 (codebook is 2MB ->
// L2-resident; each 128B line feeds 8 consecutive per-lane 16B loads -> L1
// covers the rest). NO LDS staging, NO barriers in the main loop: waves
// free-run, MFMA/VALU/L2 pipes overlap across waves instead of convoying.
// 4 waves: (rg,cg) = 64-row group x 32-col half, max B-reuse (2 MFMA/B-frag).
__global__ void __launch_bounds__(256, 2) vq_main(const float* __restrict__ z,
                                                  const float* __restrict__ cbf,
                                                  const unsigned short* __restrict__ cbb,
                                                  const float* __restrict__ enorm,
                                                  float* __restrict__ out) {
  __shared__ unsigned int minlds[2][MTILE];
  __shared__ int idx_lds[MTILE];
  __shared__ float wsum[4];
  __shared__ float zwsum[2];

  const int t = threadIdx.x;
  const int w = t >> 6;
  const int lane = t & 63;
  const int h = lane >> 5;     // half-wave
  const int eL = lane & 31;
  const int rg = w & 1;        // row group: rows rg*64..+63 of the block tile
  const int cg = w >> 1;       // col group: cols cg*32..+31 of each 64-entry tile
  const int blk = blockIdx.x;
  const int row_base = blk * MTILE + rg * 64;

  // ---- A-phase: 64 z rows (2 groups of 32) x D=256 as bf16 into registers.
  // A layout for 32x32x16: m = lane&31, k = (lane>>5)*8 + j, per 16-k step.
  uint4 afrag[2][16];
  float zn[2] = {0.f, 0.f};
#pragma unroll
  for (int g = 0; g < 2; ++g) {
    const float* rp = z + (size_t)(row_base + g * 32 + eL) * EMB_DIM + h * 8;
#pragma unroll
    for (int ks = 0; ks < 16; ++ks) {
      float4 a0 = *(const float4*)(rp + ks * 16);
      float4 a1 = *(const float4*)(rp + ks * 16 + 4);
      zn[g] += a0.x * a0.x + a0.y * a0.y + a0.z * a0.z + a0.w * a0.w
             + a1.x * a1.x + a1.y * a1.y + a1.z * a1.z + a1.w * a1.w;
      afrag[g][ks] = pack_bf8(a0, a1);
    }
    zn[g] += __shfl_xor(zn[g], 32, 64);
  }
  // Sum ||z||^2 over this wave's 64 rows (waves with cg==0 cover all 128 rows).
  if (cg == 0) {
    float zs = zn[0] + zn[1];
#pragma unroll
    for (int m = 1; m <= 16; m <<= 1) zs += __shfl_xor(zs, m, 64);
    if (lane == 0) zwsum[rg] = zs;
  }

  // Running packed argmin: top-20 bits of positive distance | 12-bit col.
  unsigned int pmin[32];
#pragma unroll
  for (int s = 0; s < 32; ++s) pmin[s] = 0xFFFFFFFFu;

  // B stream base: lane covers entry col = cg*32+eL, elements h*8.. per kstep.
  // uint4 element offset for (entry e, kstep ks): e*32 + ks*2 + h.
  const int col = cg * 32 + eL;
  const uint4* bbase = (const uint4*)cbb + (size_t)col * 32 + h;

  for (int c0 = 0; c0 < NUM_EMB; c0 += NTILE) {
    float enC = enorm[c0 + col];
    const uint4* bq = bbase + (size_t)c0 * 32;

    floatx16 acc0, acc1;
#pragma unroll
    for (int r = 0; r < 16; ++r) { acc0[r] = 0.f; acc1[r] = 0.f; }
#pragma unroll
    for (int ks = 0; ks < 16; ++ks) {
      bf16x8 b = __builtin_bit_cast(bf16x8, bq[ks * 2]);
      acc0 = __builtin_amdgcn_mfma_f32_32x32x16_bf16(
          __builtin_bit_cast(bf16x8, afrag[0][ks]), b, acc0, 0, 0, 0);
      acc1 = __builtin_amdgcn_mfma_f32_32x32x16_bf16(
          __builtin_bit_cast(bf16x8, afrag[1][ks]), b, acc1, 0, 0, 0);
    }

    // d = -2*(z.e) + (||e||^2 + C) > 0; pack top-20 bits with col index.
    unsigned int colb = (unsigned int)(c0 + col);
#pragma unroll
    for (int reg = 0; reg < 16; ++reg) {
      float d0 = fmaf(-2.f, acc0[reg], enC);
      unsigned int p0 = (__float_as_uint(d0) & 0xFFFFF000u) | colb;
      pmin[reg] = min(pmin[reg], p0);
      float d1 = fmaf(-2.f, acc1[reg], enC);
      unsigned int p1 = (__float_as_uint(d1) & 0xFFFFF000u) | colb;
      pmin[16 + reg] = min(pmin[16 + reg], p1);
    }
    // no barrier: waves free-run over the codebook stream
  }

  // Reduce over the 32 col-lanes (xor 1..16 stays within half-wave; halves
  // cover disjoint row sets). Packed u32 min = (distance, index) lexicographic
  // -> smallest-index tiebreak like np.argmin.
#pragma unroll
  for (int s = 0; s < 32; ++s) {
    unsigned int v = pmin[s];
#pragma unroll
    for (int m = 1; m <= 16; m <<= 1) {
      unsigned int o = __shfl_xor(v, m, 64);
      if (o < v) v = o;
    }
    pmin[s] = v;
  }
  // C/D layout 32x32: row = (reg&3) + 8*(reg>>2) + 4*(lane>>5), col = lane&31.
  if (eL == 0) {
#pragma unroll
    for (int s = 0; s < 32; ++s) {
      int g = s >> 4, reg = s & 15;
      int rowl = rg * 64 + g * 32 + (reg & 3) + 8 * (reg >> 2) + 4 * h;
      minlds[cg][rowl] = pmin[s];
    }
  }
  __syncthreads();

  // Combine col-halves; recover idx + distance; loss = sum(||z||^2 + d - C).
  float rl = 0.f;
  if (t < MTILE) {
    unsigned int m0 = minlds[0][t], m1 = minlds[1][t];
    unsigned int m = m1 < m0 ? m1 : m0;
    idx_lds[t] = (int)(m & 0xFFFu);
    rl = __uint_as_float(m & 0xFFFFF000u) - DCONST;
  }
#pragma unroll
  for (int m = 1; m < 64; m <<= 1) rl += __shfl_xor(rl, m, 64);
  if (lane == 0) wsum[w] = rl;
  __syncthreads();
  if (t == 0) {
    float s = (wsum[0] + wsum[1]) + (wsum[2] + wsum[3]) + zwsum[0] + zwsum[1];
    atomicAdd(out + OUT0_SIZE, s * (1.25f / (float)OUT0_SIZE));
  }

  // Gather phase: out = codebook[idx] (== z + (z_q - z) to ~3e-7).
#pragma unroll 4
  for (int j = 0; j < 32; ++j) {
    int id4 = j * 256 + t;     // float4 index within 128x256 tile
    int r = id4 >> 6, c4 = id4 & 63;
    int k = idx_lds[r];
    float4 ev = ((const float4*)(cbf + (size_t)k * EMB_DIM))[c4];
    ((float4*)(out + (size_t)(blk * MTILE + r) * EMB_DIM))[c4] = ev;
  }
}

extern "C" void kernel_launch(void* const* d_in, const int* in_sizes, int n_in,
                              void* d_out, int out_size, void* d_ws, size_t ws_size,
                              hipStream_t stream) {
  const float* z = (const float*)d_in[0];
  const float* cbf = (const float*)d_in[1];
  unsigned short* cbb = (unsigned short*)d_ws;                           // 2 MB bf16 codebook
  float* enorm = (float*)((char*)d_ws + (size_t)NUM_EMB * EMB_DIM * 2);  // +16 KB
  float* out = (float*)d_out;
  vq_prep<<<NUM_EMB / 4, 256, 0, stream>>>(cbf, cbb, enorm, out);
  vq_main<<<NVEC / MTILE, 256, 0, stream>>>(z, cbf, cbb, enorm, out);
}

// Round 7
// 299.929 us; speedup vs baseline: 1.2195x; 1.2195x over previous
//
#include <hip/hip_runtime.h>
#include <hip/hip_bf16.h>
#include <stdint.h>

#define NUM_EMB 4096
#define EMB_DIM 256
#define NVEC 65536                     // 64*32*32
#define OUT0_SIZE (NVEC * EMB_DIM)     // z_q_ste elements; loss scalar follows
#define MTILE 128                      // z rows per block
#define NTILE 64                       // codebook entries per iteration
#define DCONST 0.0625f                 // positivity shift for packed distance

typedef __bf16 bf16x8 __attribute__((ext_vector_type(8)));
typedef float floatx16 __attribute__((ext_vector_type(16)));

static __device__ __forceinline__ unsigned int f2bf(float f) {
  unsigned int u = __float_as_uint(f);
  return (u + 0x7fffu + ((u >> 16) & 1u)) >> 16;  // RNE fp32->bf16
}

// Prep: codebook fp32 -> bf16 in K-MAJOR FRAGMENT layout (ws), ||e||^2+DCONST
// (ws), zero loss slot. Packed layout: 16B chunk for (entry e, k=ks*16+h*8..)
// lives at chunk index (e>>5)*1024 + ks*64 + h*32 + (e&31). A wave's
// B-fragment load (64 lanes = h*32+eL) is then 64 CONSECUTIVE chunks = 1KB
// fully-coalesced, and consecutive ks are sequential -> pure streaming.
__global__ void __launch_bounds__(256) vq_prep(const float* __restrict__ cbf,
                                               unsigned short* __restrict__ cbb,
                                               float* __restrict__ enorm,
                                               float* __restrict__ out) {
  int w = threadIdx.x >> 6;
  int lane = threadIdx.x & 63;
  int row = blockIdx.x * 4 + w;
  float4 v = ((const float4*)(cbf + (size_t)row * EMB_DIM))[lane];
  float ss = v.x * v.x + v.y * v.y + v.z * v.z + v.w * v.w;
  ushort4 b;
  b.x = (unsigned short)f2bf(v.x);
  b.y = (unsigned short)f2bf(v.y);
  b.z = (unsigned short)f2bf(v.z);
  b.w = (unsigned short)f2bf(v.w);
  // lane covers k = 4*lane..4*lane+3: ks = lane>>2, h = (lane>>1)&1, q = lane&1
  {
    int cgrp = row >> 5, eL = row & 31;
    int ks = lane >> 2, h = (lane >> 1) & 1, q = lane & 1;
    size_t off16 = (size_t)cgrp * 1024 + ks * 64 + h * 32 + eL;
    *(ushort4*)((unsigned char*)cbb + off16 * 16 + q * 8) = b;
  }
#pragma unroll
  for (int m = 1; m < 64; m <<= 1) ss += __shfl_xor(ss, m, 64);
  if (lane == 0) enorm[row] = ss + DCONST;
  if (blockIdx.x == 0 && threadIdx.x == 0) out[OUT0_SIZE] = 0.0f;
}

// Main: distance-GEMM streaming B from L1/L2 in the packed fragment layout
// (fully coalesced 1KB wave-loads; 16KB col-slice is L1-resident and shared
// by the paired row-group wave). NO LDS staging, NO main-loop barriers:
// waves free-run and drift, so one wave's argmin epilogue overlaps the other
// wave's MFMA burst on the same SIMD. 4 waves: 64-row group x 32-col half.
__global__ void __launch_bounds__(256, 2) vq_main(const float* __restrict__ z,
                                                  const float* __restrict__ cbf,
                                                  const unsigned short* __restrict__ cbb,
                                                  const float* __restrict__ enorm,
                                                  float* __restrict__ out) {
  __shared__ unsigned int minlds[2][MTILE];
  __shared__ int idx_lds[MTILE];
  __shared__ float wsum[4];
  __shared__ float zwsum[2];

  const int t = threadIdx.x;
  const int w = t >> 6;
  const int lane = t & 63;
  const int h = lane >> 5;     // half-wave
  const int eL = lane & 31;
  const int rg = w & 1;        // row group: rows rg*64..+63 of the block tile
  const int cg = w >> 1;       // col group: cols cg*32..+31 of each 64-entry tile
  const int blk = blockIdx.x;
  const int row_base = blk * MTILE + rg * 64;

  // ---- A-phase: 64 z rows (2 groups of 32) x D=256 as bf16 into registers.
  // A layout for 32x32x16: m = lane&31, k = (lane>>5)*8 + j, per 16-k step.
  uint4 afrag[2][16];
  float zn[2] = {0.f, 0.f};
#pragma unroll
  for (int g = 0; g < 2; ++g) {
    const float* rp = z + (size_t)(row_base + g * 32 + eL) * EMB_DIM + h * 8;
#pragma unroll
    for (int ks = 0; ks < 16; ++ks) {
      float4 a0 = *(const float4*)(rp + ks * 16);
      float4 a1 = *(const float4*)(rp + ks * 16 + 4);
      zn[g] += a0.x * a0.x + a0.y * a0.y + a0.z * a0.z + a0.w * a0.w
             + a1.x * a1.x + a1.y * a1.y + a1.z * a1.z + a1.w * a1.w;
      uint4 r;
      r.x = f2bf(a0.x) | (f2bf(a0.y) << 16);
      r.y = f2bf(a0.z) | (f2bf(a0.w) << 16);
      r.z = f2bf(a1.x) | (f2bf(a1.y) << 16);
      r.w = f2bf(a1.z) | (f2bf(a1.w) << 16);
      afrag[g][ks] = r;
    }
    zn[g] += __shfl_xor(zn[g], 32, 64);
  }
  // Sum ||z||^2 over this wave's 64 rows (waves with cg==0 cover all 128 rows).
  if (cg == 0) {
    float zs = zn[0] + zn[1];
#pragma unroll
    for (int m = 1; m <= 16; m <<= 1) zs += __shfl_xor(zs, m, 64);
    if (lane == 0) zwsum[rg] = zs;
  }

  // Running packed argmin: top-20 bits of positive distance | 12-bit col.
  unsigned int pmin[32];
#pragma unroll
  for (int s = 0; s < 32; ++s) pmin[s] = 0xFFFFFFFFu;

  // B stream: this wave's 32-col slice of each tile. Chunk index for
  // (cgrp, ks, lane) = cgrp*1024 + ks*64 + h*32 + eL  (16B chunks).
  const int col = cg * 32 + eL;
  const uint4* bbase = (const uint4*)cbb + (size_t)(h * 32 + eL);

  for (int c0 = 0; c0 < NUM_EMB; c0 += NTILE) {
    float enC = enorm[c0 + col];
    const uint4* bq = bbase + ((size_t)(c0 >> 5) + cg) * 1024;

    floatx16 acc0, acc1;
#pragma unroll
    for (int r = 0; r < 16; ++r) { acc0[r] = 0.f; acc1[r] = 0.f; }
#pragma unroll
    for (int ks = 0; ks < 16; ++ks) {
      bf16x8 b = __builtin_bit_cast(bf16x8, bq[ks * 64]);
      acc0 = __builtin_amdgcn_mfma_f32_32x32x16_bf16(
          __builtin_bit_cast(bf16x8, afrag[0][ks]), b, acc0, 0, 0, 0);
      acc1 = __builtin_amdgcn_mfma_f32_32x32x16_bf16(
          __builtin_bit_cast(bf16x8, afrag[1][ks]), b, acc1, 0, 0, 0);
    }

    // d = -2*(z.e) + (||e||^2 + C) > 0; pack top-20 bits with col index.
    // (d & M) | (colb & ~M) is the canonical v_bfi_b32 pattern.
    unsigned int colb = (unsigned int)(c0 + col);
#pragma unroll
    for (int reg = 0; reg < 16; ++reg) {
      float d0 = fmaf(-2.f, acc0[reg], enC);
      unsigned int p0 = (__float_as_uint(d0) & 0xFFFFF000u) | (colb & 0x00000FFFu);
      pmin[reg] = min(pmin[reg], p0);
      float d1 = fmaf(-2.f, acc1[reg], enC);
      unsigned int p1 = (__float_as_uint(d1) & 0xFFFFF000u) | (colb & 0x00000FFFu);
      pmin[16 + reg] = min(pmin[16 + reg], p1);
    }
    // no barrier: waves free-run over the codebook stream
  }

  // Reduce over the 32 col-lanes (xor 1..16 stays within half-wave; halves
  // cover disjoint row sets). Packed u32 min = (distance, index) lexicographic
  // -> smallest-index tiebreak like np.argmin.
#pragma unroll
  for (int s = 0; s < 32; ++s) {
    unsigned int v = pmin[s];
#pragma unroll
    for (int m = 1; m <= 16; m <<= 1) {
      unsigned int o = __shfl_xor(v, m, 64);
      if (o < v) v = o;
    }
    pmin[s] = v;
  }
  // C/D layout 32x32: row = (reg&3) + 8*(reg>>2) + 4*(lane>>5), col = lane&31.
  if (eL == 0) {
#pragma unroll
    for (int s = 0; s < 32; ++s) {
      int g = s >> 4, reg = s & 15;
      int rowl = rg * 64 + g * 32 + (reg & 3) + 8 * (reg >> 2) + 4 * h;
      minlds[cg][rowl] = pmin[s];
    }
  }
  __syncthreads();

  // Combine col-halves; recover idx + distance; loss = sum(||z||^2 + d - C).
  float rl = 0.f;
  if (t < MTILE) {
    unsigned int m0 = minlds[0][t], m1 = minlds[1][t];
    unsigned int m = m1 < m0 ? m1 : m0;
    idx_lds[t] = (int)(m & 0xFFFu);
    rl = __uint_as_float(m & 0xFFFFF000u) - DCONST;
  }
#pragma unroll
  for (int m = 1; m < 64; m <<= 1) rl += __shfl_xor(rl, m, 64);
  if (lane == 0) wsum[w] = rl;
  __syncthreads();
  if (t == 0) {
    float s = (wsum[0] + wsum[1]) + (wsum[2] + wsum[3]) + zwsum[0] + zwsum[1];
    atomicAdd(out + OUT0_SIZE, s * (1.25f / (float)OUT0_SIZE));
  }

  // Gather phase: out = codebook[idx] (== z + (z_q - z) to ~3e-7).
#pragma unroll 4
  for (int j = 0; j < 32; ++j) {
    int id4 = j * 256 + t;     // float4 index within 128x256 tile
    int r = id4 >> 6, c4 = id4 & 63;
    int k = idx_lds[r];
    float4 ev = ((const float4*)(cbf + (size_t)k * EMB_DIM))[c4];
    ((float4*)(out + (size_t)(blk * MTILE + r) * EMB_DIM))[c4] = ev;
  }
}

extern "C" void kernel_launch(void* const* d_in, const int* in_sizes, int n_in,
                              void* d_out, int out_size, void* d_ws, size_t ws_size,
                              hipStream_t stream) {
  const float* z = (const float*)d_in[0];
  const float* cbf = (const float*)d_in[1];
  unsigned short* cbb = (unsigned short*)d_ws;                           // 2 MB packed bf16 codebook
  float* enorm = (float*)((char*)d_ws + (size_t)NUM_EMB * EMB_DIM * 2);  // +16 KB
  float* out = (float*)d_out;
  vq_prep<<<NUM_EMB / 4, 256, 0, stream>>>(cbf, cbb, enorm, out);
  vq_main<<<NVEC / MTILE, 256, 0, stream>>>(z, cbf, cbb, enorm, out);
}

// Round 8
// 264.286 us; speedup vs baseline: 1.3839x; 1.1349x over previous
//
#include <hip/hip_runtime.h>
#include <hip/hip_bf16.h>
#include <stdint.h>

#define NUM_EMB 4096
#define EMB_DIM 256
#define NVEC 65536                     // 64*32*32
#define OUT0_SIZE (NVEC * EMB_DIM)     // z_q_ste elements; loss scalar follows
#define MTILE 128                      // z rows per block
#define NTILE 64                       // codebook entries per iteration
#define DCONST 0.0625f                 // positivity shift for packed distance

typedef __bf16 bf16x8 __attribute__((ext_vector_type(8)));
typedef float floatx16 __attribute__((ext_vector_type(16)));

static __device__ __forceinline__ unsigned int f2bf(float f) {
  unsigned int u = __float_as_uint(f);
  return (u + 0x7fffu + ((u >> 16) & 1u)) >> 16;  // RNE fp32->bf16
}

// Prep: codebook fp32 -> bf16 in K-MAJOR FRAGMENT layout (ws), ||e||^2+DCONST
// (ws), zero loss slot. Packed layout: 16B chunk for (entry e, k=ks*16+h*8..)
// lives at chunk index (e>>5)*1024 + ks*64 + h*32 + (e&31). A wave's
// B-fragment load (64 lanes = h*32+eL) is then 64 CONSECUTIVE chunks = 1KB
// fully-coalesced, and consecutive ks are sequential -> pure streaming.
__global__ void __launch_bounds__(256) vq_prep(const float* __restrict__ cbf,
                                               unsigned short* __restrict__ cbb,
                                               float* __restrict__ enorm,
                                               float* __restrict__ out) {
  int w = threadIdx.x >> 6;
  int lane = threadIdx.x & 63;
  int row = blockIdx.x * 4 + w;
  float4 v = ((const float4*)(cbf + (size_t)row * EMB_DIM))[lane];
  float ss = v.x * v.x + v.y * v.y + v.z * v.z + v.w * v.w;
  ushort4 b;
  b.x = (unsigned short)f2bf(v.x);
  b.y = (unsigned short)f2bf(v.y);
  b.z = (unsigned short)f2bf(v.z);
  b.w = (unsigned short)f2bf(v.w);
  // lane covers k = 4*lane..4*lane+3: ks = lane>>2, h = (lane>>1)&1, q = lane&1
  {
    int cgrp = row >> 5, eL = row & 31;
    int ks = lane >> 2, h = (lane >> 1) & 1, q = lane & 1;
    size_t off16 = (size_t)cgrp * 1024 + ks * 64 + h * 32 + eL;
    *(ushort4*)((unsigned char*)cbb + off16 * 16 + q * 8) = b;
  }
#pragma unroll
  for (int m = 1; m < 64; m <<= 1) ss += __shfl_xor(ss, m, 64);
  if (lane == 0) enorm[row] = ss + DCONST;
  if (blockIdx.x == 0 && threadIdx.x == 0) out[OUT0_SIZE] = 0.0f;
}

// Main: distance-GEMM streaming B from L1/L2 in the packed fragment layout
// with an 8-DEEP ROLLING REGISTER WINDOW: step ks consumes bw[ks&7] and
// immediately reloads that slot for data 8 steps ahead (2nd half of this
// tile, then 1st half of the next tile). ~8 loads in flight -> ~1000cy L2
// latency coverage. NO LDS staging, NO main-loop barriers: waves free-run,
// epilogue VALU of one wave overlaps MFMA of the other on the same SIMD.
// 4 waves: 64-row group x 32-col half (2 MFMA per B-fragment).
__global__ void __launch_bounds__(256, 2) vq_main(const float* __restrict__ z,
                                                  const float* __restrict__ cbf,
                                                  const unsigned short* __restrict__ cbb,
                                                  const float* __restrict__ enorm,
                                                  float* __restrict__ out) {
  __shared__ unsigned int minlds[2][MTILE];
  __shared__ int idx_lds[MTILE];
  __shared__ float wsum[4];
  __shared__ float zwsum[2];

  const int t = threadIdx.x;
  const int w = t >> 6;
  const int lane = t & 63;
  const int h = lane >> 5;     // half-wave
  const int eL = lane & 31;
  const int rg = w & 1;        // row group: rows rg*64..+63 of the block tile
  const int cg = w >> 1;       // col group: cols cg*32..+31 of each 64-entry tile
  const int blk = blockIdx.x;
  const int row_base = blk * MTILE + rg * 64;

  // ---- A-phase: 64 z rows (2 groups of 32) x D=256 as bf16 into registers.
  // A layout for 32x32x16: m = lane&31, k = (lane>>5)*8 + j, per 16-k step.
  uint4 afrag[2][16];
  float zn[2] = {0.f, 0.f};
#pragma unroll
  for (int g = 0; g < 2; ++g) {
    const float* rp = z + (size_t)(row_base + g * 32 + eL) * EMB_DIM + h * 8;
#pragma unroll
    for (int ks = 0; ks < 16; ++ks) {
      float4 a0 = *(const float4*)(rp + ks * 16);
      float4 a1 = *(const float4*)(rp + ks * 16 + 4);
      zn[g] += a0.x * a0.x + a0.y * a0.y + a0.z * a0.z + a0.w * a0.w
             + a1.x * a1.x + a1.y * a1.y + a1.z * a1.z + a1.w * a1.w;
      uint4 r;
      r.x = f2bf(a0.x) | (f2bf(a0.y) << 16);
      r.y = f2bf(a0.z) | (f2bf(a0.w) << 16);
      r.z = f2bf(a1.x) | (f2bf(a1.y) << 16);
      r.w = f2bf(a1.z) | (f2bf(a1.w) << 16);
      afrag[g][ks] = r;
    }
    zn[g] += __shfl_xor(zn[g], 32, 64);
  }
  // Sum ||z||^2 over this wave's 64 rows (waves with cg==0 cover all 128 rows).
  if (cg == 0) {
    float zs = zn[0] + zn[1];
#pragma unroll
    for (int m = 1; m <= 16; m <<= 1) zs += __shfl_xor(zs, m, 64);
    if (lane == 0) zwsum[rg] = zs;
  }

  // Running packed argmin: top-20 bits of positive distance | 12-bit col.
  unsigned int pmin[32];
#pragma unroll
  for (int s = 0; s < 32; ++s) pmin[s] = 0xFFFFFFFFu;

  // B stream: wave's 32-col slice of tile tt is packed chunk (2*tt+cg),
  // 16KB contiguous. Per-lane slot address (uint4): chunkbase + ks*64 + lo.
  const int lo = h * 32 + eL;
  const uint4* cbb16 = (const uint4*)cbb;
  const uint4* cb = cbb16 + (size_t)cg * 1024 + lo;       // tile 0 chunk
  const uint4* cb0 = cb;                                  // wrap target

  // Preload window slots 0..7 (first half of tile 0).
  uint4 bw[8];
#pragma unroll
  for (int j = 0; j < 8; ++j) bw[j] = cb[j * 64];

  float enC = enorm[cg * 32 + eL];
  float enN = enC;

  for (int tt = 0; tt < 64; ++tt) {
    const uint4* cbn = (tt < 63) ? (cb + 2048) : cb0;     // next tile (wrap: in-bounds, never consumed)
    if (tt < 63) enN = enorm[(tt + 1) * 64 + cg * 32 + eL];

    floatx16 acc0, acc1;
#pragma unroll
    for (int r = 0; r < 16; ++r) { acc0[r] = 0.f; acc1[r] = 0.f; }

    // First half: consume slot ks, reload it with this tile's ks+8.
#pragma unroll
    for (int ks = 0; ks < 8; ++ks) {
      bf16x8 b = __builtin_bit_cast(bf16x8, bw[ks]);
      acc0 = __builtin_amdgcn_mfma_f32_32x32x16_bf16(
          __builtin_bit_cast(bf16x8, afrag[0][ks]), b, acc0, 0, 0, 0);
      acc1 = __builtin_amdgcn_mfma_f32_32x32x16_bf16(
          __builtin_bit_cast(bf16x8, afrag[1][ks]), b, acc1, 0, 0, 0);
      bw[ks] = cb[(ks + 8) * 64];
    }
    // Second half: consume slot ks-8, reload it with NEXT tile's ks-8.
#pragma unroll
    for (int ks = 8; ks < 16; ++ks) {
      bf16x8 b = __builtin_bit_cast(bf16x8, bw[ks - 8]);
      acc0 = __builtin_amdgcn_mfma_f32_32x32x16_bf16(
          __builtin_bit_cast(bf16x8, afrag[0][ks]), b, acc0, 0, 0, 0);
      acc1 = __builtin_amdgcn_mfma_f32_32x32x16_bf16(
          __builtin_bit_cast(bf16x8, afrag[1][ks]), b, acc1, 0, 0, 0);
      bw[ks - 8] = cbn[(ks - 8) * 64];
    }

    // d = -2*(z.e) + (||e||^2 + C) > 0; pack top-20 bits with col index
    // ((d & M) | (colb & ~M) fuses to v_bfi_b32).
    unsigned int colb = (unsigned int)(tt * 64 + cg * 32 + eL);
#pragma unroll
    for (int reg = 0; reg < 16; ++reg) {
      float d0 = fmaf(-2.f, acc0[reg], enC);
      unsigned int p0 = (__float_as_uint(d0) & 0xFFFFF000u) | (colb & 0x00000FFFu);
      pmin[reg] = min(pmin[reg], p0);
      float d1 = fmaf(-2.f, acc1[reg], enC);
      unsigned int p1 = (__float_as_uint(d1) & 0xFFFFF000u) | (colb & 0x00000FFFu);
      pmin[16 + reg] = min(pmin[16 + reg], p1);
    }

    cb = cbn;
    enC = enN;
    // no barrier: waves free-run over the codebook stream
  }

  // Reduce over the 32 col-lanes (xor 1..16 stays within half-wave; halves
  // cover disjoint row sets). Packed u32 min = (distance, index) lexicographic
  // -> smallest-index tiebreak like np.argmin.
#pragma unroll
  for (int s = 0; s < 32; ++s) {
    unsigned int v = pmin[s];
#pragma unroll
    for (int m = 1; m <= 16; m <<= 1) {
      unsigned int o = __shfl_xor(v, m, 64);
      if (o < v) v = o;
    }
    pmin[s] = v;
  }
  // C/D layout 32x32: row = (reg&3) + 8*(reg>>2) + 4*(lane>>5), col = lane&31.
  if (eL == 0) {
#pragma unroll
    for (int s = 0; s < 32; ++s) {
      int g = s >> 4, reg = s & 15;
      int rowl = rg * 64 + g * 32 + (reg & 3) + 8 * (reg >> 2) + 4 * h;
      minlds[cg][rowl] = pmin[s];
    }
  }
  __syncthreads();

  // Combine col-halves; recover idx + distance; loss = sum(||z||^2 + d - C).
  float rl = 0.f;
  if (t < MTILE) {
    unsigned int m0 = minlds[0][t], m1 = minlds[1][t];
    unsigned int m = m1 < m0 ? m1 : m0;
    idx_lds[t] = (int)(m & 0xFFFu);
    rl = __uint_as_float(m & 0xFFFFF000u) - DCONST;
  }
#pragma unroll
  for (int m = 1; m < 64; m <<= 1) rl += __shfl_xor(rl, m, 64);
  if (lane == 0) wsum[w] = rl;
  __syncthreads();
  if (t == 0) {
    float s = (wsum[0] + wsum[1]) + (wsum[2] + wsum[3]) + zwsum[0] + zwsum[1];
    atomicAdd(out + OUT0_SIZE, s * (1.25f / (float)OUT0_SIZE));
  }

  // Gather phase: out = codebook[idx] (== z + (z_q - z) to ~3e-7).
#pragma unroll 4
  for (int j = 0; j < 32; ++j) {
    int id4 = j * 256 + t;     // float4 index within 128x256 tile
    int r = id4 >> 6, c4 = id4 & 63;
    int k = idx_lds[r];
    float4 ev = ((const float4*)(cbf + (size_t)k * EMB_DIM))[c4];
    ((float4*)(out + (size_t)(blk * MTILE + r) * EMB_DIM))[c4] = ev;
  }
}

extern "C" void kernel_launch(void* const* d_in, const int* in_sizes, int n_in,
                              void* d_out, int out_size, void* d_ws, size_t ws_size,
                              hipStream_t stream) {
  const float* z = (const float*)d_in[0];
  const float* cbf = (const float*)d_in[1];
  unsigned short* cbb = (unsigned short*)d_ws;                           // 2 MB packed bf16 codebook
  float* enorm = (float*)((char*)d_ws + (size_t)NUM_EMB * EMB_DIM * 2);  // +16 KB
  float* out = (float*)d_out;
  vq_prep<<<NUM_EMB / 4, 256, 0, stream>>>(cbf, cbb, enorm, out);
  vq_main<<<NVEC / MTILE, 256, 0, stream>>>(z, cbf, cbb, enorm, out);
}